// Round 7
// baseline (279.456 us; speedup 1.0000x reference)
//
#include <hip/hip_runtime.h>

#define B_SZ 8
#define T_SZ 2048
#define C_SZ 1024

typedef __attribute__((ext_vector_type(8))) short short8;
typedef __attribute__((ext_vector_type(8))) unsigned short ushort8;
typedef __attribute__((ext_vector_type(4))) float f32x4;

__device__ __forceinline__ unsigned short f2bf(float x) {
  union { float f; unsigned u; } v; v.f = x;
  unsigned r = v.u + 0x7FFFu + ((v.u >> 16) & 1u);  // RNE
  return (unsigned short)(r >> 16);
}
__device__ __forceinline__ float bf2f(unsigned short h) {
  union { unsigned u; float f; } v; v.u = ((unsigned)h) << 16;
  return v.f;
}

// async global->LDS, 16B/lane; LDS base wave-uniform, global addr per-lane.
__device__ __forceinline__ void gload16(const void* g, void* l) {
  __builtin_amdgcn_global_load_lds(
      (const __attribute__((address_space(1))) unsigned int*)(uintptr_t)g,
      (__attribute__((address_space(3))) unsigned int*)(uintptr_t)l, 16, 0, 0);
}

// T1: bijective XCD-chunked swizzle (nwg % 8 == 0 in all our grids).
__device__ __forceinline__ int xcd_swz(int orig, int nwg) {
  return (orig & 7) * (nwg >> 3) + (orig >> 3);
}

#define WAITV(N) asm volatile("s_waitcnt vmcnt(" #N ")" ::: "memory")
#define BAR1                            \
  {                                     \
    asm volatile("" ::: "memory");      \
    __builtin_amdgcn_s_barrier();       \
    __builtin_amdgcn_sched_barrier(0);  \
    asm volatile("" ::: "memory");      \
  }
#define BAR2                            \
  {                                     \
    asm volatile("" ::: "memory");      \
    __builtin_amdgcn_s_barrier();       \
    asm volatile("" ::: "memory");      \
  }

// ---------------------------------------------------------------------------
// 8-phase NT-GEMM core with register prefetch (R6, frozen; HW-verified,
// 0 bank conflicts, ~900 TF at K=1024). See R5/R6 notes for the vmcnt ledger.
// ---------------------------------------------------------------------------
template <int LDA, int LDB>
__device__ __forceinline__ void nt8p(const unsigned short* __restrict__ Ab,
                                     const unsigned short* __restrict__ Bb,
                                     const int NT, unsigned short* lds,
                                     f32x4 (&acc)[2][4][4]) {
  const int lane = threadIdx.x & 63;
  const int wid = threadIdx.x >> 6;
  const int wr = wid >> 2;
  const int wc = wid & 3;
  const int fr = lane & 15;
  const int fq = lane >> 4;

  // ---- staging source pointers (pre-swizzled global addresses) ----
  const int aslot = ((lane & 7) ^ (lane >> 3)) * 8;
  const int rr0 = (wid * 2 + 0) * 8 + (lane >> 3);
  const int rr1 = (wid * 2 + 1) * 8 + (lane >> 3);
  const unsigned short* pA0 =
      Ab + (size_t)((rr0 >> 6) * 128 + (rr0 & 63)) * LDA + aslot;
  const unsigned short* pA1 =
      Ab + (size_t)((rr1 >> 6) * 128 + (rr1 & 63)) * LDA + aslot;
  const int bslot = ((lane & 3) ^ ((lane >> 3) & 3)) * 8;
  const unsigned short* pB0 =
      Bb + (size_t)((wid * 2 + 0) * 16 + (lane >> 2)) * LDB + bslot;
  const unsigned short* pB1 =
      Bb + (size_t)((wid * 2 + 1) * 16 + (lane >> 2)) * LDB + bslot;
  const int ldsC0 = (wid * 2 + 0) * 512;
  const int ldsC1 = (wid * 2 + 1) * 512;

  // ---- fragment-read bases ----
  const int arb = wr * 4096 + fr * 64;
  const int asw0 = ((0 * 4 + fq) ^ (fr & 7)) * 8;
  const int asw1 = ((1 * 4 + fq) ^ (fr & 7)) * 8;
  const int brb = 16384 + (wc * 64 + fr) * 32 + ((fq ^ ((fr >> 1) & 3)) * 8);

  short8 afq[4], afp[4], bf0[4], bf1[4];

#define STG_A(d, h, kt)                                           \
  {                                                               \
    gload16(pA0 + (size_t)(h) * 64 * LDA + (size_t)(kt) * 64,     \
            lds + (d) * 32768 + (h) * 8192 + ldsC0);              \
    gload16(pA1 + (size_t)(h) * 64 * LDA + (size_t)(kt) * 64,     \
            lds + (d) * 32768 + (h) * 8192 + ldsC1);              \
  }
#define STG_B(d, kh, kt)                                          \
  {                                                               \
    gload16(pB0 + (kh) * 32 + (size_t)(kt) * 64,                  \
            lds + (d) * 32768 + 16384 + (kh) * 8192 + ldsC0);     \
    gload16(pB1 + (kh) * 32 + (size_t)(kt) * 64,                  \
            lds + (d) * 32768 + 16384 + (kh) * 8192 + ldsC1);     \
  }
#define RD_A(dst, d, h, s)                                        \
  _Pragma("unroll") for (int mb = 0; mb < 4; ++mb) dst[mb] =      \
      *(const short8*)&lds[(d) * 32768 + (h) * 8192 + arb +       \
                           mb * 1024 + ((s) ? asw1 : asw0)];
#define RD_B(dst, d, s)                                           \
  _Pragma("unroll") for (int nb = 0; nb < 4; ++nb) dst[nb] =      \
      *(const short8*)&lds[(d) * 32768 + (s) * 8192 + brb + nb * 512];
#define MMQ(r, AF, BF)                                            \
  __builtin_amdgcn_s_setprio(1);                                  \
  _Pragma("unroll") for (int mb = 0; mb < 4; ++mb)                \
  _Pragma("unroll") for (int nb = 0; nb < 4; ++nb)                \
  acc[r][mb][nb] = __builtin_amdgcn_mfma_f32_16x16x32_bf16(       \
      AF[mb], BF[nb], acc[r][mb][nb], 0, 0, 0);                   \
  __builtin_amdgcn_s_setprio(0);

#define TILE_STEP(d, dn, TT)                                                  \
  {                                                                           \
    const int tp1 = ((TT) + 1 < NT) ? (TT) + 1 : NT - 1;                      \
    const int tp2 = ((TT) + 2 < NT) ? (TT) + 2 : NT - 1;                      \
    /* P0 */                                                                  \
    RD_A(afp, d, 1, 0);                                                       \
    STG_B(dn, 1, tp1);                                                        \
    BAR1; MMQ(0, afq, bf0); BAR2;                                             \
    /* P1 */                                                                  \
    WAITV(8);                                                                 \
    RD_A(afq, d, 0, 1); RD_B(bf1, d, 1);                                      \
    STG_A(dn, 1, tp1);                                                        \
    BAR1; MMQ(1, afp, bf0); BAR2;                                             \
    /* P2 */                                                                  \
    WAITV(8);                                                                 \
    RD_A(afp, d, 1, 1);                                                       \
    STG_B(d, 0, tp2);                                                         \
    BAR1; MMQ(0, afq, bf1); BAR2;                                             \
    /* P3 */                                                                  \
    WAITV(6);                                                                 \
    RD_A(afq, dn, 0, 0); RD_B(bf0, dn, 0);                                    \
    STG_A(d, 0, tp2);                                                         \
    BAR1; MMQ(1, afp, bf1); BAR2;                                             \
  }

  // prologue: oldest-first, mirrors steady-state in-flight set
  const int t1 = (NT > 1) ? 1 : 0;
  STG_A(0, 0, 0);
  STG_B(0, 0, 0);
  STG_B(0, 1, 0);
  STG_A(0, 1, 0);
  STG_B(1, 0, t1);
  STG_A(1, 0, t1);
  WAITV(8);  // A-h0(0), B-k0(0) landed
  BAR2;
  RD_A(afq, 0, 0, 0);
  RD_B(bf0, 0, 0);

  for (int T = 0; T < NT; T += 2) {
    TILE_STEP(0, 1, T);
    TILE_STEP(1, 0, T + 1);
  }
#undef STG_A
#undef STG_B
#undef RD_A
#undef RD_B
#undef MMQ
#undef TILE_STEP
}

// Epilogue helper: dump one 32-row sub-pass of acc into the wave's padded
// LDS region ldw[32][66] (f32). Rows rl = mb2*16 + fq*4 + j, cols nb*16+fr.
// Stride 66 -> dump is 2-way bank aliasing (free), readback uniform 8/bank.
#define EPI_DUMP(r, mh)                                               \
  _Pragma("unroll") for (int mb2 = 0; mb2 < 2; ++mb2)                 \
  _Pragma("unroll") for (int nb = 0; nb < 4; ++nb)                    \
  _Pragma("unroll") for (int j = 0; j < 4; ++j)                       \
      ldw[(mb2 * 16 + fq * 4 + j) * 66 + nb * 16 + fr] =              \
          acc[r][(mh) * 2 + mb2][nb][j];

// ---------------------------------------------------------------------------
// Kernel: x fp32 -> bf16
// ---------------------------------------------------------------------------
__global__ __launch_bounds__(256) void convert_x(const float* __restrict__ x,
                                                 unsigned short* __restrict__ Xb,
                                                 int n8) {
  for (int i = blockIdx.x * blockDim.x + threadIdx.x; i < n8;
       i += gridDim.x * blockDim.x) {
    const float4* p = (const float4*)(x + (size_t)i * 8);
    float4 a = p[0], b = p[1];
    ushort8 u;
    u[0] = f2bf(a.x); u[1] = f2bf(a.y); u[2] = f2bf(a.z); u[3] = f2bf(a.w);
    u[4] = f2bf(b.x); u[5] = f2bf(b.y); u[6] = f2bf(b.z); u[7] = f2bf(b.w);
    *(ushort8*)(Xb + (size_t)i * 8) = u;
  }
}

// ---------------------------------------------------------------------------
// Kernel: W fp32 [K][N] -> Wt bf16 [N][K]
// ---------------------------------------------------------------------------
__global__ __launch_bounds__(256) void transpose_w(
    const float* __restrict__ Wq, const float* __restrict__ Wk,
    const float* __restrict__ Wv, unsigned short* __restrict__ Wt) {
  const int z = blockIdx.z;
  const float* W = z == 0 ? Wq : (z == 1 ? Wk : Wv);
  unsigned short* O = Wt + (size_t)z * C_SZ * C_SZ;
  __shared__ float tl[32][33];
  const int bx = blockIdx.x * 32;  // n
  const int by = blockIdx.y * 32;  // k
  const int tx = threadIdx.x & 31;
  const int ty = threadIdx.x >> 5;  // 0..7
#pragma unroll
  for (int j = 0; j < 4; ++j)
    tl[ty + j * 8][tx] = W[(size_t)(by + ty + j * 8) * C_SZ + bx + tx];
  __syncthreads();
#pragma unroll
  for (int j = 0; j < 4; ++j)
    O[(size_t)(bx + ty + j * 8) * C_SZ + by + tx] = f2bf(tl[tx][ty + j * 8]);
}

// ---------------------------------------------------------------------------
// Kernel: fused QKV GEMM. z=0,1: Y_z = Xb @ Wt_z^T + b_z row-major bf16.
// z=2: writes V TRANSPOSED (Vt[b][c][t]) directly -- transpose_v eliminated.
// ---------------------------------------------------------------------------
__global__ __launch_bounds__(512, 2) void qkv_fused(
    const unsigned short* __restrict__ Xb, const unsigned short* __restrict__ Wt,
    const float* __restrict__ bq, const float* __restrict__ bk,
    const float* __restrict__ bv, unsigned short* __restrict__ Q,
    unsigned short* __restrict__ K, unsigned short* __restrict__ Vt) {
  __shared__ unsigned short lds[65536] __attribute__((aligned(128)));
  const int wg = xcd_swz(blockIdx.x, 3 * 64 * 4);
  const int z = wg >> 8;
  const int rem = wg & 255;
  const int m0 = (rem >> 2) * 256;
  const int n0 = (rem & 3) * 256;

  f32x4 acc[2][4][4] = {};
  nt8p<C_SZ, C_SZ>(Xb + (size_t)m0 * C_SZ,
                   Wt + (size_t)z * C_SZ * C_SZ + (size_t)n0 * C_SZ,
                   C_SZ / 64, lds, acc);

  const int lane = threadIdx.x & 63;
  const int wid = threadIdx.x >> 6;
  const int wr = wid >> 2, wc = wid & 3;
  const int fr = lane & 15, fq = lane >> 4;

  WAITV(0);          // drain tail dummy stages before LDS reuse
  __syncthreads();
  float* ldw = (float*)lds + wid * 2112;  // 32x66 f32 per-wave region

  if (z < 2) {
    unsigned short* Y = (z == 0) ? Q : K;
    const float* bias = (z == 0) ? bq : bk;
    const int cbase = n0 + wc * 64 + (lane & 7) * 8;
    float bb[8];
#pragma unroll
    for (int k = 0; k < 8; ++k) bb[k] = bias[cbase + k];
#pragma unroll
    for (int r = 0; r < 2; ++r)
#pragma unroll
      for (int mh = 0; mh < 2; ++mh) {
        EPI_DUMP(r, mh);
        const int rbase = m0 + wr * 128 + r * 64 + mh * 32;
#pragma unroll
        for (int i = 0; i < 4; ++i) {
          const int rl = i * 8 + (lane >> 3);
          const f32x4 lo = *(const f32x4*)&ldw[rl * 66 + (lane & 7) * 8];
          const f32x4 hi = *(const f32x4*)&ldw[rl * 66 + (lane & 7) * 8 + 4];
          ushort8 o;
#pragma unroll
          for (int k = 0; k < 4; ++k) o[k] = f2bf(lo[k] + bb[k]);
#pragma unroll
          for (int k = 0; k < 4; ++k) o[4 + k] = f2bf(hi[k] + bb[4 + k]);
          *(ushort8*)&Y[(size_t)(rbase + rl) * C_SZ + cbase] = o;
        }
      }
  } else {
    // Vt epilogue: column-read the LDS region, write Vt[b][c][t] rows.
    const int b2 = m0 >> 11;
    const int tb = m0 & (T_SZ - 1);
    unsigned short* Vtb = Vt + (size_t)b2 * C_SZ * T_SZ;
    const int cb = n0 + wc * 64;
    float bv4[4];
#pragma unroll
    for (int i = 0; i < 4; ++i) bv4[i] = bv[cb + (lane >> 2) + i * 16];
#pragma unroll
    for (int r = 0; r < 2; ++r)
#pragma unroll
      for (int mh = 0; mh < 2; ++mh) {
        EPI_DUMP(r, mh);
        const int t0 = tb + wr * 128 + r * 64 + mh * 32 + (lane & 3) * 8;
#pragma unroll
        for (int i = 0; i < 4; ++i) {
          const int c = (lane >> 2) + i * 16;
          ushort8 o;
#pragma unroll
          for (int k = 0; k < 8; ++k)
            o[k] = f2bf(ldw[((lane & 3) * 8 + k) * 66 + c] + bv4[i]);
          *(ushort8*)&Vtb[(size_t)(cb + c) * T_SZ + t0] = o;
        }
      }
  }
}

// ---------------------------------------------------------------------------
// Kernel: S = scale * Q @ K^T (causal block skip), bf16 out
// ---------------------------------------------------------------------------
__global__ __launch_bounds__(512, 2) void scores_gemm(
    const unsigned short* __restrict__ Q, const unsigned short* __restrict__ Km,
    unsigned short* __restrict__ S, float scale) {
  const int wg = xcd_swz(blockIdx.x, B_SZ * 8 * 8);
  const int b = wg >> 6;
  const int rem = wg & 63;
  const int mt = rem >> 3, nt = rem & 7;
  if (nt > mt) return;
  const int m0 = mt * 256, n0 = nt * 256;
  __shared__ unsigned short lds[65536] __attribute__((aligned(128)));

  f32x4 acc[2][4][4] = {};
  nt8p<C_SZ, C_SZ>(Q + (size_t)b * T_SZ * C_SZ + (size_t)m0 * C_SZ,
                   Km + (size_t)b * T_SZ * C_SZ + (size_t)n0 * C_SZ,
                   C_SZ / 64, lds, acc);

  unsigned short* Sb = S + (size_t)b * T_SZ * T_SZ;
  const int lane = threadIdx.x & 63;
  const int wid = threadIdx.x >> 6;
  const int wr = wid >> 2, wc = wid & 3;
  const int fr = lane & 15, fq = lane >> 4;

  WAITV(0);
  __syncthreads();
  float* ldw = (float*)lds + wid * 2112;
  const int cbase = n0 + wc * 64 + (lane & 7) * 8;
#pragma unroll
  for (int r = 0; r < 2; ++r)
#pragma unroll
    for (int mh = 0; mh < 2; ++mh) {
      EPI_DUMP(r, mh);
      const int rbase = m0 + wr * 128 + r * 64 + mh * 32;
#pragma unroll
      for (int i = 0; i < 4; ++i) {
        const int rl = i * 8 + (lane >> 3);
        const f32x4 lo = *(const f32x4*)&ldw[rl * 66 + (lane & 7) * 8];
        const f32x4 hi = *(const f32x4*)&ldw[rl * 66 + (lane & 7) * 8 + 4];
        ushort8 o;
#pragma unroll
        for (int k = 0; k < 4; ++k) o[k] = f2bf(lo[k] * scale);
#pragma unroll
        for (int k = 0; k < 4; ++k) o[4 + k] = f2bf(hi[k] * scale);
        *(ushort8*)&Sb[(size_t)(rbase + rl) * T_SZ + cbase] = o;
      }
    }
}

// ---------------------------------------------------------------------------
// Kernel: causal softmax, vectorized ushort8; loads only the causal prefix,
// zero-pads to next 256 (pv BK granularity).
// ---------------------------------------------------------------------------
__device__ __forceinline__ float wredmax(float v) {
#pragma unroll
  for (int o = 32; o > 0; o >>= 1) v = fmaxf(v, __shfl_xor(v, o, 64));
  return v;
}
__device__ __forceinline__ float wredsum(float v) {
#pragma unroll
  for (int o = 32; o > 0; o >>= 1) v += __shfl_xor(v, o, 64);
  return v;
}

__global__ __launch_bounds__(256) void softmax_causal(
    unsigned short* __restrict__ S) {
  const int row = blockIdx.x;
  const int b = row >> 11;
  const int tq = row & (T_SZ - 1);
  unsigned short* sr = S + (size_t)b * T_SZ * T_SZ + (size_t)tq * T_SZ;
  const int len = tq + 1;
  const int wlen = (len + 255) & ~255;
  const int tid = threadIdx.x;
  const int lane = tid & 63;
  const int wid = tid >> 6;
  const int i0 = tid * 8;
  __shared__ float red[4];

  float v[8];
  float mx = -1e30f;
  if (i0 < len) {
    const ushort8 raw = *(const ushort8*)(sr + i0);
#pragma unroll
    for (int j = 0; j < 8; ++j) {
      v[j] = (i0 + j < len) ? bf2f(raw[j]) : -1e30f;
      mx = fmaxf(mx, v[j]);
    }
  } else {
#pragma unroll
    for (int j = 0; j < 8; ++j) v[j] = -1e30f;
  }
  mx = wredmax(mx);
  if (lane == 0) red[wid] = mx;
  __syncthreads();
  mx = fmaxf(fmaxf(red[0], red[1]), fmaxf(red[2], red[3]));
  __syncthreads();

  float sm = 0.f;
#pragma unroll
  for (int j = 0; j < 8; ++j) {
    v[j] = __expf(v[j] - mx);
    sm += v[j];
  }
  sm = wredsum(sm);
  if (lane == 0) red[wid] = sm;
  __syncthreads();
  sm = red[0] + red[1] + red[2] + red[3];
  const float inv = 1.f / sm;

  if (i0 < wlen) {
    ushort8 o;
#pragma unroll
    for (int j = 0; j < 8; ++j)
      o[j] = (i0 + j < len) ? f2bf(v[j] * inv) : (unsigned short)0;
    *(ushort8*)(sr + i0) = o;
  }
}

// ---------------------------------------------------------------------------
// Kernel: O = P @ Vt^T (NT, causal K-cap), fp32 out, coalesced f32x4 stores
// ---------------------------------------------------------------------------
__global__ __launch_bounds__(512, 2) void pv_gemm(
    const unsigned short* __restrict__ P, const unsigned short* __restrict__ Vt,
    float* __restrict__ O) {
  const int wg = xcd_swz(blockIdx.x, B_SZ * 8 * 4);
  const int b = wg >> 5;
  const int rem = wg & 31;
  const int mt = rem >> 2, nt = rem & 3;
  const int m0 = mt * 256, n0 = nt * 256;
  __shared__ unsigned short lds[65536] __attribute__((aligned(128)));

  f32x4 acc[2][4][4] = {};
  nt8p<T_SZ, T_SZ>(P + (size_t)b * T_SZ * T_SZ + (size_t)m0 * T_SZ,
                   Vt + (size_t)b * C_SZ * T_SZ + (size_t)n0 * T_SZ,
                   4 * (mt + 1), lds, acc);

  float* Ob = O + (size_t)b * T_SZ * C_SZ;
  const int lane = threadIdx.x & 63;
  const int wid = threadIdx.x >> 6;
  const int wr = wid >> 2, wc = wid & 3;
  const int fr = lane & 15, fq = lane >> 4;

  WAITV(0);
  __syncthreads();
  float* ldw = (float*)lds + wid * 2112;
  const int cbase = n0 + wc * 64 + (lane & 15) * 4;
#pragma unroll
  for (int r = 0; r < 2; ++r)
#pragma unroll
    for (int mh = 0; mh < 2; ++mh) {
      EPI_DUMP(r, mh);
      const int rbase = m0 + wr * 128 + r * 64 + mh * 32;
#pragma unroll
      for (int i = 0; i < 8; ++i) {
        const int rl = i * 4 + (lane >> 4);
        const f32x4 v = *(const f32x4*)&ldw[rl * 66 + (lane & 15) * 4];
        *(f32x4*)&Ob[(size_t)(rbase + rl) * C_SZ + cbase] = v;
      }
    }
}

// ---------------------------------------------------------------------------
extern "C" void kernel_launch(void* const* d_in, const int* in_sizes, int n_in,
                              void* d_out, int out_size, void* d_ws,
                              size_t ws_size, hipStream_t stream) {
  (void)in_sizes; (void)n_in; (void)out_size; (void)ws_size;
  const float* x = (const float*)d_in[0];
  const float* Wq = (const float*)d_in[1];
  const float* bq = (const float*)d_in[2];
  const float* Wk = (const float*)d_in[3];
  const float* bk = (const float*)d_in[4];
  const float* Wv = (const float*)d_in[5];
  const float* bv = (const float*)d_in[6];
  float* out = (float*)d_out;

  const size_t TC = (size_t)B_SZ * T_SZ * C_SZ;  // 16,777,216
  unsigned short* Q = (unsigned short*)d_ws;
  unsigned short* K = Q + TC;
  unsigned short* Vt = K + TC;  // V slot now holds V transposed directly
  unsigned short* S = Vt + TC;  // B*T*T ushorts
  unsigned short* Xb = S;       // phase-1 alias (dead once scores runs)
  unsigned short* Wt = S + TC;  // phase-1 alias, 3M ushorts

  const float scale = 0.022097086912079608f;  // 2048^-0.5

  hipLaunchKernelGGL(convert_x, dim3(2048), dim3(256), 0, stream, x, Xb,
                     (int)(TC / 8));
  hipLaunchKernelGGL(transpose_w, dim3(32, 32, 3), dim3(256), 0, stream, Wq,
                     Wk, Wv, Wt);
  hipLaunchKernelGGL(qkv_fused, dim3(3 * 64 * 4), dim3(512), 0, stream, Xb, Wt,
                     bq, bk, bv, Q, K, Vt);
  hipLaunchKernelGGL(scores_gemm, dim3(B_SZ * 8 * 8), dim3(512), 0, stream, Q,
                     K, S, scale);
  hipLaunchKernelGGL(softmax_causal, dim3(B_SZ * T_SZ), dim3(256), 0, stream,
                     S);
  hipLaunchKernelGGL(pv_gemm, dim3(B_SZ * 8 * 4), dim3(512), 0, stream, S, Vt,
                     out);
}

// Round 10
// 255.724 us; speedup vs baseline: 1.0928x; 1.0928x over previous
//
#include <hip/hip_runtime.h>

#define B_SZ 8
#define T_SZ 2048
#define C_SZ 1024

typedef __attribute__((ext_vector_type(8))) short short8;
typedef __attribute__((ext_vector_type(8))) unsigned short ushort8;
typedef __attribute__((ext_vector_type(4))) float f32x4;

__device__ __forceinline__ unsigned short f2bf(float x) {
  union { float f; unsigned u; } v; v.f = x;
  unsigned r = v.u + 0x7FFFu + ((v.u >> 16) & 1u);  // RNE
  return (unsigned short)(r >> 16);
}
__device__ __forceinline__ float bf2f(unsigned short h) {
  union { unsigned u; float f; } v; v.u = ((unsigned)h) << 16;
  return v.f;
}

// async global->LDS, 16B/lane; LDS base wave-uniform, global addr per-lane.
__device__ __forceinline__ void gload16(const void* g, void* l) {
  __builtin_amdgcn_global_load_lds(
      (const __attribute__((address_space(1))) unsigned int*)(uintptr_t)g,
      (__attribute__((address_space(3))) unsigned int*)(uintptr_t)l, 16, 0, 0);
}

// T1: bijective XCD-chunked swizzle (nwg % 8 == 0 in all our grids).
__device__ __forceinline__ int xcd_swz(int orig, int nwg) {
  return (orig & 7) * (nwg >> 3) + (orig >> 3);
}

#define WAITV(N) asm volatile("s_waitcnt vmcnt(" #N ")" ::: "memory")
#define BAR1                            \
  {                                     \
    asm volatile("" ::: "memory");      \
    __builtin_amdgcn_s_barrier();       \
    __builtin_amdgcn_sched_barrier(0);  \
    asm volatile("" ::: "memory");      \
  }
#define BAR2                            \
  {                                     \
    asm volatile("" ::: "memory");      \
    __builtin_amdgcn_s_barrier();       \
    asm volatile("" ::: "memory");      \
  }

// ---------------------------------------------------------------------------
// 8-phase NT-GEMM core — R5 version (race-free ledger, HW-verified clean).
// 256x256 tile, BK=64, 8 waves (2M x 4N), 16x16x32 bf16 MFMA, 2 LDS dbufs.
//
// CRITICAL LEDGER DISCIPLINE (lesson of R6-R9): a wave's fragment read of
// slot X is safe only if the STAGING wave executed a vmcnt wait that drains X
// *before a barrier* that precedes the reading phase (cross-wave publish).
// Hence waits are placed AFTER the MFMA, before BAR2 (hidden behind compute):
//   P0: reads A-h0(g),B-k0(g)   [drained at (g-1).P3 WAITV(8), published]
//       MM; WAITV(6) drains B-k1(g),A-h1(g); BAR2  -> publishes for P1/P2
//   P3: MM; WAITV(8) drains B-k0(g+1),A-h0(g+1); BAR2 -> publishes for next P0
// Do NOT "optimize" waits to phase-start-before-reads (R6 bug: stochastic
// cross-wave corruption -> NaN under memory congestion).
//
// CALLER CONTRACT: core returns with up to 8 dummy tail stages in flight —
// caller MUST WAITV(0) before any exit path / LDS reuse.
// ---------------------------------------------------------------------------
template <int LDA, int LDB>
__device__ __forceinline__ void nt8p(const unsigned short* __restrict__ Ab,
                                     const unsigned short* __restrict__ Bb,
                                     const int NT, unsigned short* lds,
                                     f32x4 (&acc)[2][4][4]) {
  const int lane = threadIdx.x & 63;
  const int wid = threadIdx.x >> 6;
  const int wr = wid >> 2;
  const int wc = wid & 3;
  const int fr = lane & 15;
  const int fq = lane >> 4;

  // ---- staging source pointers (pre-swizzled global addresses) ----
  const int aslot = ((lane & 7) ^ (lane >> 3)) * 8;
  const int rr0 = (wid * 2 + 0) * 8 + (lane >> 3);
  const int rr1 = (wid * 2 + 1) * 8 + (lane >> 3);
  const unsigned short* pA0 =
      Ab + (size_t)((rr0 >> 6) * 128 + (rr0 & 63)) * LDA + aslot;
  const unsigned short* pA1 =
      Ab + (size_t)((rr1 >> 6) * 128 + (rr1 & 63)) * LDA + aslot;
  const int bslot = ((lane & 3) ^ ((lane >> 3) & 3)) * 8;
  const unsigned short* pB0 =
      Bb + (size_t)((wid * 2 + 0) * 16 + (lane >> 2)) * LDB + bslot;
  const unsigned short* pB1 =
      Bb + (size_t)((wid * 2 + 1) * 16 + (lane >> 2)) * LDB + bslot;
  const int ldsC0 = (wid * 2 + 0) * 512;
  const int ldsC1 = (wid * 2 + 1) * 512;

  // ---- fragment-read bases ----
  const int arb = wr * 4096 + fr * 64;
  const int asw0 = ((0 * 4 + fq) ^ (fr & 7)) * 8;
  const int asw1 = ((1 * 4 + fq) ^ (fr & 7)) * 8;
  const int brb = 16384 + (wc * 64 + fr) * 32 + ((fq ^ ((fr >> 1) & 3)) * 8);

#define STG_A(d, h, kt)                                           \
  {                                                               \
    gload16(pA0 + (size_t)(h) * 64 * LDA + (size_t)(kt) * 64,     \
            lds + (d) * 32768 + (h) * 8192 + ldsC0);              \
    gload16(pA1 + (size_t)(h) * 64 * LDA + (size_t)(kt) * 64,     \
            lds + (d) * 32768 + (h) * 8192 + ldsC1);              \
  }
#define STG_B(d, kh, kt)                                          \
  {                                                               \
    gload16(pB0 + (kh) * 32 + (size_t)(kt) * 64,                  \
            lds + (d) * 32768 + 16384 + (kh) * 8192 + ldsC0);     \
    gload16(pB1 + (kh) * 32 + (size_t)(kt) * 64,                  \
            lds + (d) * 32768 + 16384 + (kh) * 8192 + ldsC1);     \
  }
#define LDAF(d, r, s)                                             \
  _Pragma("unroll") for (int mb = 0; mb < 4; ++mb) af[mb] =       \
      *(const short8*)&lds[(d) * 32768 + (r) * 8192 + arb +       \
                           mb * 1024 + ((s) ? asw1 : asw0)];
#define LDBF(d, s)                                                \
  _Pragma("unroll") for (int nb = 0; nb < 4; ++nb) bf[nb] =       \
      *(const short8*)&lds[(d) * 32768 + (s) * 8192 + brb + nb * 512];
#define MM(r)                                                     \
  __builtin_amdgcn_s_setprio(1);                                  \
  _Pragma("unroll") for (int mb = 0; mb < 4; ++mb)                \
  _Pragma("unroll") for (int nb = 0; nb < 4; ++nb)                \
  acc[r][mb][nb] = __builtin_amdgcn_mfma_f32_16x16x32_bf16(       \
      af[mb], bf[nb], acc[r][mb][nb], 0, 0, 0);                   \
  __builtin_amdgcn_s_setprio(0);
#define TILE_STEP(d, dn, TT)                                                 \
  {                                                                          \
    const int tp1 = ((TT) + 1 < NT) ? (TT) + 1 : NT - 1;                     \
    const int tp2 = ((TT) + 2 < NT) ? (TT) + 2 : NT - 1;                     \
    short8 af[4], bf[4];                                                     \
    LDAF(d, 0, 0); LDBF(d, 0); STG_B(dn, 1, tp1); BAR1; MM(0); WAITV(6); BAR2; \
    LDAF(d, 1, 0); STG_A(dn, 1, tp1); BAR1; MM(1); BAR2;                     \
    LDAF(d, 0, 1); LDBF(d, 1); STG_B(d, 0, tp2); BAR1; MM(0); BAR2;          \
    LDAF(d, 1, 1); STG_A(d, 0, tp2); BAR1; MM(1); WAITV(8); BAR2;            \
  }

  // prologue: issue order = steady-state order for tiles "-2,-1"
  const int t1 = (NT > 1) ? 1 : 0;
  STG_B(0, 0, 0);
  STG_A(0, 0, 0);
  STG_B(0, 1, 0);
  STG_A(0, 1, 0);
  STG_B(1, 0, t1);
  STG_A(1, 0, t1);
  WAITV(8);  // oldest 2 half-tiles (B-k0(0), A-h0(0)) landed
  BAR2;

  for (int T = 0; T < NT; T += 2) {
    TILE_STEP(0, 1, T);
    TILE_STEP(1, 0, T + 1);
  }
#undef STG_A
#undef STG_B
#undef LDAF
#undef LDBF
#undef MM
#undef TILE_STEP
}

// Epilogue helper (used ONLY for the Vt column-write, which genuinely needs a
// transpose): dump one 32-row sub-pass of acc into the wave's padded LDS
// region ldw[32][66] f32.
#define EPI_DUMP(r, mh)                                               \
  _Pragma("unroll") for (int mb2 = 0; mb2 < 2; ++mb2)                 \
  _Pragma("unroll") for (int nb = 0; nb < 4; ++nb)                    \
  _Pragma("unroll") for (int j = 0; j < 4; ++j)                       \
      ldw[(mb2 * 16 + fq * 4 + j) * 66 + nb * 16 + fr] =              \
          acc[r][(mh) * 2 + mb2][nb][j];

// ---------------------------------------------------------------------------
// Kernel: x fp32 -> bf16
// ---------------------------------------------------------------------------
__global__ __launch_bounds__(256) void convert_x(const float* __restrict__ x,
                                                 unsigned short* __restrict__ Xb,
                                                 int n8) {
  for (int i = blockIdx.x * blockDim.x + threadIdx.x; i < n8;
       i += gridDim.x * blockDim.x) {
    const float4* p = (const float4*)(x + (size_t)i * 8);
    float4 a = p[0], b = p[1];
    ushort8 u;
    u[0] = f2bf(a.x); u[1] = f2bf(a.y); u[2] = f2bf(a.z); u[3] = f2bf(a.w);
    u[4] = f2bf(b.x); u[5] = f2bf(b.y); u[6] = f2bf(b.z); u[7] = f2bf(b.w);
    *(ushort8*)(Xb + (size_t)i * 8) = u;
  }
}

// ---------------------------------------------------------------------------
// Kernel: W fp32 [K][N] -> Wt bf16 [N][K]
// ---------------------------------------------------------------------------
__global__ __launch_bounds__(256) void transpose_w(
    const float* __restrict__ Wq, const float* __restrict__ Wk,
    const float* __restrict__ Wv, unsigned short* __restrict__ Wt) {
  const int z = blockIdx.z;
  const float* W = z == 0 ? Wq : (z == 1 ? Wk : Wv);
  unsigned short* O = Wt + (size_t)z * C_SZ * C_SZ;
  __shared__ float tl[32][33];
  const int bx = blockIdx.x * 32;  // n
  const int by = blockIdx.y * 32;  // k
  const int tx = threadIdx.x & 31;
  const int ty = threadIdx.x >> 5;  // 0..7
#pragma unroll
  for (int j = 0; j < 4; ++j)
    tl[ty + j * 8][tx] = W[(size_t)(by + ty + j * 8) * C_SZ + bx + tx];
  __syncthreads();
#pragma unroll
  for (int j = 0; j < 4; ++j)
    O[(size_t)(bx + ty + j * 8) * C_SZ + by + tx] = f2bf(tl[tx][ty + j * 8]);
}

// ---------------------------------------------------------------------------
// Kernel: fused QKV GEMM. z=0,1: direct scattered bf16 stores. z=2: writes V
// TRANSPOSED (Vt[b][c][t]) via per-wave LDS transpose (transpose_v fused).
// ---------------------------------------------------------------------------
__global__ __launch_bounds__(512, 2) void qkv_fused(
    const unsigned short* __restrict__ Xb, const unsigned short* __restrict__ Wt,
    const float* __restrict__ bq, const float* __restrict__ bk,
    const float* __restrict__ bv, unsigned short* __restrict__ Q,
    unsigned short* __restrict__ K, unsigned short* __restrict__ Vt) {
  __shared__ unsigned short lds[65536] __attribute__((aligned(128)));
  const int wg = xcd_swz(blockIdx.x, 3 * 64 * 4);
  const int z = wg >> 8;
  const int rem = wg & 255;
  const int m0 = (rem >> 2) * 256;
  const int n0 = (rem & 3) * 256;

  f32x4 acc[2][4][4] = {};
  nt8p<C_SZ, C_SZ>(Xb + (size_t)m0 * C_SZ,
                   Wt + (size_t)z * C_SZ * C_SZ + (size_t)n0 * C_SZ,
                   C_SZ / 64, lds, acc);
  WAITV(0);  // drain tail dummy stages — caller contract

  const int lane = threadIdx.x & 63;
  const int wid = threadIdx.x >> 6;
  const int wr = wid >> 2, wc = wid & 3;
  const int fr = lane & 15, fq = lane >> 4;

  if (z < 2) {
    unsigned short* Y = (z == 0) ? Q : K;
    const float* bias = (z == 0) ? bq : bk;
#pragma unroll
    for (int r = 0; r < 2; ++r)
#pragma unroll
      for (int nb = 0; nb < 4; ++nb) {
        const int col = n0 + wc * 64 + nb * 16 + fr;
        const float bvv = bias[col];
#pragma unroll
        for (int mb = 0; mb < 4; ++mb) {
          const int row0 = m0 + wr * 128 + r * 64 + mb * 16 + fq * 4;
#pragma unroll
          for (int j = 0; j < 4; ++j)
            Y[(size_t)(row0 + j) * C_SZ + col] = f2bf(acc[r][mb][nb][j] + bvv);
        }
      }
  } else {
    // Vt epilogue: per-wave LDS transpose, write Vt[b][c][t] rows.
    __syncthreads();  // all waves drained; LDS now safe to reuse
    float* ldw = (float*)lds + wid * 2112;  // 32x66 f32 per-wave region
    const int b2 = m0 >> 11;
    const int tb = m0 & (T_SZ - 1);
    unsigned short* Vtb = Vt + (size_t)b2 * C_SZ * T_SZ;
    const int cb = n0 + wc * 64;
    float bv4[4];
#pragma unroll
    for (int i = 0; i < 4; ++i) bv4[i] = bv[cb + (lane >> 2) + i * 16];
#pragma unroll
    for (int r = 0; r < 2; ++r)
#pragma unroll
      for (int mh = 0; mh < 2; ++mh) {
        EPI_DUMP(r, mh);
        const int t0 = tb + wr * 128 + r * 64 + mh * 32 + (lane & 3) * 8;
#pragma unroll
        for (int i = 0; i < 4; ++i) {
          const int c = (lane >> 2) + i * 16;
          ushort8 o;
#pragma unroll
          for (int k = 0; k < 8; ++k)
            o[k] = f2bf(ldw[((lane & 3) * 8 + k) * 66 + c] + bv4[i]);
          *(ushort8*)&Vtb[(size_t)(cb + c) * T_SZ + t0] = o;
        }
      }
  }
}

// ---------------------------------------------------------------------------
// Kernel: S = scale * Q @ K^T (causal block skip), bf16 out (direct stores)
// ---------------------------------------------------------------------------
__global__ __launch_bounds__(512, 2) void scores_gemm(
    const unsigned short* __restrict__ Q, const unsigned short* __restrict__ Km,
    unsigned short* __restrict__ S, float scale) {
  const int wg = xcd_swz(blockIdx.x, B_SZ * 8 * 8);
  const int b = wg >> 6;
  const int rem = wg & 63;
  const int mt = rem >> 3, nt = rem & 7;
  if (nt > mt) return;
  const int m0 = mt * 256, n0 = nt * 256;
  __shared__ unsigned short lds[65536] __attribute__((aligned(128)));

  f32x4 acc[2][4][4] = {};
  nt8p<C_SZ, C_SZ>(Q + (size_t)b * T_SZ * C_SZ + (size_t)m0 * C_SZ,
                   Km + (size_t)b * T_SZ * C_SZ + (size_t)n0 * C_SZ,
                   C_SZ / 64, lds, acc);
  WAITV(0);  // drain tail dummy stages — caller contract

  unsigned short* Sb = S + (size_t)b * T_SZ * T_SZ;
  const int lane = threadIdx.x & 63;
  const int wid = threadIdx.x >> 6;
  const int wr = wid >> 2, wc = wid & 3;
  const int fr = lane & 15, fq = lane >> 4;
#pragma unroll
  for (int r = 0; r < 2; ++r)
#pragma unroll
    for (int nb = 0; nb < 4; ++nb) {
      const int col = n0 + wc * 64 + nb * 16 + fr;
#pragma unroll
      for (int mb = 0; mb < 4; ++mb) {
        const int row0 = m0 + wr * 128 + r * 64 + mb * 16 + fq * 4;
#pragma unroll
        for (int j = 0; j < 4; ++j)
          Sb[(size_t)(row0 + j) * T_SZ + col] = f2bf(acc[r][mb][nb][j] * scale);
      }
    }
}

// ---------------------------------------------------------------------------
// Kernel: causal softmax, vectorized ushort8; loads only the causal prefix,
// zero-pads to next 256 (pv BK granularity).
// ---------------------------------------------------------------------------
__device__ __forceinline__ float wredmax(float v) {
#pragma unroll
  for (int o = 32; o > 0; o >>= 1) v = fmaxf(v, __shfl_xor(v, o, 64));
  return v;
}
__device__ __forceinline__ float wredsum(float v) {
#pragma unroll
  for (int o = 32; o > 0; o >>= 1) v += __shfl_xor(v, o, 64);
  return v;
}

__global__ __launch_bounds__(256) void softmax_causal(
    unsigned short* __restrict__ S) {
  const int row = blockIdx.x;
  const int b = row >> 11;
  const int tq = row & (T_SZ - 1);
  unsigned short* sr = S + (size_t)b * T_SZ * T_SZ + (size_t)tq * T_SZ;
  const int len = tq + 1;
  const int wlen = (len + 255) & ~255;
  const int tid = threadIdx.x;
  const int lane = tid & 63;
  const int wid = tid >> 6;
  const int i0 = tid * 8;
  __shared__ float red[4];

  float v[8];
  float mx = -1e30f;
  if (i0 < len) {
    const ushort8 raw = *(const ushort8*)(sr + i0);
#pragma unroll
    for (int j = 0; j < 8; ++j) {
      v[j] = (i0 + j < len) ? bf2f(raw[j]) : -1e30f;
      mx = fmaxf(mx, v[j]);
    }
  } else {
#pragma unroll
    for (int j = 0; j < 8; ++j) v[j] = -1e30f;
  }
  mx = wredmax(mx);
  if (lane == 0) red[wid] = mx;
  __syncthreads();
  mx = fmaxf(fmaxf(red[0], red[1]), fmaxf(red[2], red[3]));
  __syncthreads();

  float sm = 0.f;
#pragma unroll
  for (int j = 0; j < 8; ++j) {
    v[j] = __expf(v[j] - mx);
    sm += v[j];
  }
  sm = wredsum(sm);
  if (lane == 0) red[wid] = sm;
  __syncthreads();
  sm = red[0] + red[1] + red[2] + red[3];
  const float inv = 1.f / sm;

  if (i0 < wlen) {
    ushort8 o;
#pragma unroll
    for (int j = 0; j < 8; ++j)
      o[j] = (i0 + j < len) ? f2bf(v[j] * inv) : (unsigned short)0;
    *(ushort8*)(sr + i0) = o;
  }
}

// ---------------------------------------------------------------------------
// Kernel: O = P @ Vt^T (NT, causal K-cap), fp32 out (direct stores)
// ---------------------------------------------------------------------------
__global__ __launch_bounds__(512, 2) void pv_gemm(
    const unsigned short* __restrict__ P, const unsigned short* __restrict__ Vt,
    float* __restrict__ O) {
  const int wg = xcd_swz(blockIdx.x, B_SZ * 8 * 4);
  const int b = wg >> 5;
  const int rem = wg & 31;
  const int mt = rem >> 2, nt = rem & 3;
  const int m0 = mt * 256, n0 = nt * 256;
  __shared__ unsigned short lds[65536] __attribute__((aligned(128)));

  f32x4 acc[2][4][4] = {};
  nt8p<T_SZ, T_SZ>(P + (size_t)b * T_SZ * T_SZ + (size_t)m0 * T_SZ,
                   Vt + (size_t)b * C_SZ * T_SZ + (size_t)n0 * T_SZ,
                   4 * (mt + 1), lds, acc);
  WAITV(0);  // drain tail dummy stages — caller contract

  float* Ob = O + (size_t)b * T_SZ * C_SZ;
  const int lane = threadIdx.x & 63;
  const int wid = threadIdx.x >> 6;
  const int wr = wid >> 2, wc = wid & 3;
  const int fr = lane & 15, fq = lane >> 4;
#pragma unroll
  for (int r = 0; r < 2; ++r)
#pragma unroll
    for (int nb = 0; nb < 4; ++nb) {
      const int col = n0 + wc * 64 + nb * 16 + fr;
#pragma unroll
      for (int mb = 0; mb < 4; ++mb) {
        const int row0 = m0 + wr * 128 + r * 64 + mb * 16 + fq * 4;
#pragma unroll
        for (int j = 0; j < 4; ++j)
          Ob[(size_t)(row0 + j) * C_SZ + col] = acc[r][mb][nb][j];
      }
    }
}

// ---------------------------------------------------------------------------
extern "C" void kernel_launch(void* const* d_in, const int* in_sizes, int n_in,
                              void* d_out, int out_size, void* d_ws,
                              size_t ws_size, hipStream_t stream) {
  (void)in_sizes; (void)n_in; (void)out_size; (void)ws_size;
  const float* x = (const float*)d_in[0];
  const float* Wq = (const float*)d_in[1];
  const float* bq = (const float*)d_in[2];
  const float* Wk = (const float*)d_in[3];
  const float* bk = (const float*)d_in[4];
  const float* Wv = (const float*)d_in[5];
  const float* bv = (const float*)d_in[6];
  float* out = (float*)d_out;

  const size_t TC = (size_t)B_SZ * T_SZ * C_SZ;  // 16,777,216
  unsigned short* Q = (unsigned short*)d_ws;
  unsigned short* K = Q + TC;
  unsigned short* Vt = K + TC;  // V stored transposed directly by qkv z=2
  unsigned short* S = Vt + TC;  // B*T*T ushorts
  unsigned short* Xb = S;       // phase-1 alias (dead once scores runs)
  unsigned short* Wt = S + TC;  // phase-1 alias, 3M ushorts

  const float scale = 0.022097086912079608f;  // 2048^-0.5

  hipLaunchKernelGGL(convert_x, dim3(2048), dim3(256), 0, stream, x, Xb,
                     (int)(TC / 8));
  hipLaunchKernelGGL(transpose_w, dim3(32, 32, 3), dim3(256), 0, stream, Wq,
                     Wk, Wv, Wt);
  hipLaunchKernelGGL(qkv_fused, dim3(3 * 64 * 4), dim3(512), 0, stream, Xb, Wt,
                     bq, bk, bv, Q, K, Vt);
  hipLaunchKernelGGL(scores_gemm, dim3(B_SZ * 8 * 8), dim3(512), 0, stream, Q,
                     K, S, scale);
  hipLaunchKernelGGL(softmax_causal, dim3(B_SZ * T_SZ), dim3(256), 0, stream,
                     S);
  hipLaunchKernelGGL(pv_gemm, dim3(B_SZ * 8 * 4), dim3(512), 0, stream, S, Vt,
                     out);
}